// Round 2
// baseline (15624.512 us; speedup 1.0000x reference)
//
#include <hip/hip_runtime.h>
#include <math.h>

// Problem constants (from reference setup_inputs)
#define S_LEN 256
#define BATCH 64
#define WLEN  16
#define EC    64     // char emb dim
#define HC    128    // char hidden
#define HWID  512    // word hidden
#define TT    32     // tags
#define DD    557    // word-lstm input dim = 1 + 300 + 2*128
#define NSEQ  16384  // B*S char sequences
#define NSB   16384  // S*B word positions
#define GC    512    // 4*HC
#define GW    2048   // 4*HWID
#define CHUNK 32     // word-scan chunk (steps) for Ax staging
#define CROWS (CHUNK*BATCH)   // 2048 rows per chunk GEMM

__device__ __forceinline__ float sigf(float x){ return 1.f/(1.f+__expf(-x)); }

// ---------------- generic fp32 tiled GEMM: C = act(A(MxK) * B(NxK)^T + bias) ----------
// BM=128, BN=64, BK=16, 256 threads, 8x4 micro-tile per thread.
#define BM 128
#define BN 64
#define BK 16
__global__ __launch_bounds__(256)
void gemm_nt(const float* __restrict__ A, int lda,
             const float* __restrict__ Bm, int ldb,
             float* __restrict__ C, int ldc,
             int M, int N, int K,
             const float* __restrict__ bias, int act)
{
    __shared__ float As[BK][BM+4];
    __shared__ float Bs[BK][BN+4];
    const int tid = threadIdx.x;
    const int m0 = blockIdx.x * BM;
    const int n0 = blockIdx.y * BN;
    const int tr = tid >> 4;   // 0..15
    const int tc = tid & 15;   // 0..15
    float acc[8][4];
    #pragma unroll
    for (int i=0;i<8;i++)
        #pragma unroll
        for(int j=0;j<4;j++) acc[i][j]=0.f;

    for (int k0 = 0; k0 < K; k0 += BK) {
        #pragma unroll
        for (int i = 0; i < 8; i++) {           // A tile 128x16
            int e = i*256 + tid;
            int m = e >> 4, k = e & 15;
            int gm = m0 + m, gk = k0 + k;
            float v = 0.f;
            if (gm < M && gk < K) v = A[(long)gm*lda + gk];
            As[k][m] = v;
        }
        #pragma unroll
        for (int i = 0; i < 4; i++) {           // B tile 64x16
            int e = i*256 + tid;
            int n = e >> 4, k = e & 15;
            int gn = n0 + n, gk = k0 + k;
            float v = 0.f;
            if (gn < N && gk < K) v = Bm[(long)gn*ldb + gk];
            Bs[k][n] = v;
        }
        __syncthreads();
        #pragma unroll
        for (int k = 0; k < BK; k++) {
            float a[8], b[4];
            #pragma unroll
            for (int i=0;i<8;i++) a[i]=As[k][tr*8+i];
            #pragma unroll
            for (int j=0;j<4;j++) b[j]=Bs[k][tc*4+j];
            #pragma unroll
            for (int i=0;i<8;i++)
                #pragma unroll
                for (int j=0;j<4;j++)
                    acc[i][j] += a[i]*b[j];
        }
        __syncthreads();
    }
    #pragma unroll
    for (int i=0;i<8;i++){
        int m = m0 + tr*8 + i;
        if (m >= M) continue;
        #pragma unroll
        for (int j=0;j<4;j++){
            int n = n0 + tc*4 + j;
            if (n >= N) continue;
            float v = acc[i][j];
            if (bias) v += bias[n];
            if (act==1) v = tanhf(v);
            C[(long)m*ldc + n] = v;
        }
    }
}

// ---------------- P = char_emb(128x64) @ Wih^T(64x512) per direction -------------------
__global__ void char_pmat(const float* __restrict__ ce,
                          const float* __restrict__ wf, const float* __restrict__ wb,
                          float* __restrict__ Pf, float* __restrict__ Pb)
{
    int gid = blockIdx.x*blockDim.x + threadIdx.x;
    if (gid >= 2*128*GC) return;
    int d = gid >> 16;        // 65536 per direction
    int r = gid & 65535;
    int v = r >> 9, j = r & 511;
    const float* wW = d ? wb : wf;
    float s = 0.f;
    for (int e=0;e<EC;e++) s += ce[v*EC+e]*wW[j*EC+e];
    (d ? Pb : Pf)[r] = s;
}

__global__ void bias_sum(const float* __restrict__ a1, const float* __restrict__ a2,
                         const float* __restrict__ b1, const float* __restrict__ b2,
                         float* __restrict__ of, float* __restrict__ ob, int n)
{
    int i = blockIdx.x*blockDim.x+threadIdx.x;
    if (i < n){ of[i]=a1[i]+a2[i]; ob[i]=b1[i]+b2[i]; }
}

__global__ void zero_f(float* __restrict__ p, int n)
{
    int i = blockIdx.x*blockDim.x+threadIdx.x;
    if (i < n) p[i] = 0.f;
}

// ---------------- char LSTM pointwise step ---------------------------------------------
// Z: (NSEQ x 512) recurrent gates (h @ Whh^T); P adds input projection by char id.
__global__ __launch_bounds__(256)
void char_pw(const float* __restrict__ Z, const float* __restrict__ P,
             const float* __restrict__ bih, const float* __restrict__ bhh,
             const int* __restrict__ ci,
             float* __restrict__ h, float* __restrict__ c,
             float* __restrict__ X, int t, int islast, int xoff)
{
    int gid = blockIdx.x*blockDim.x + threadIdx.x;
    if (gid >= NSEQ*HC) return;
    int n = gid >> 7, cell = gid & 127;
    int cid = ci[n*WLEN + t];           // char_inputs flat (B,S,W): n*16+t
    const float* Pr = P + cid*GC;
    int zb = n*GC;
    float zi = Z[zb+cell]     + Pr[cell]     + bih[cell]     + bhh[cell];
    float zf = Z[zb+128+cell] + Pr[128+cell] + bih[128+cell] + bhh[128+cell];
    float zg = Z[zb+256+cell] + Pr[256+cell] + bih[256+cell] + bhh[256+cell];
    float zo = Z[zb+384+cell] + Pr[384+cell] + bih[384+cell] + bhh[384+cell];
    float cp = c[gid];
    float cn = sigf(zf)*cp + sigf(zi)*tanhf(zg);
    float hv = sigf(zo)*tanhf(cn);
    c[gid]=cn; h[gid]=hv;
    if (islast){                         // final hidden -> x char-feature slot
        int b = n >> 8, s = n & 255;     // n = b*S + s
        X[(size_t)(s*BATCH+b)*DD + xoff + cell] = hv;
    }
}

// ---------------- x assembly: word emb + cap emb ---------------------------------------
__global__ void x_fill(const int* __restrict__ wid, const int* __restrict__ cap,
                       const float* __restrict__ wemb, const float* __restrict__ cemb,
                       float* __restrict__ X)
{
    int gid = blockIdx.x*blockDim.x+threadIdx.x;
    int sb = gid / 304, e = gid % 304;
    if (sb >= NSB) return;
    if (e < 300)       X[(size_t)sb*DD + e]   = wemb[(size_t)wid[sb]*300 + e];
    else if (e == 300) X[(size_t)sb*DD + 556] = cemb[cap[sb]];
}

// ---------------- fused word-LSTM step (both directions in one launch) -----------------
// grid 128: dir(2) x slice(64).  Block owns 8 cells (32 gate rows) x all 64 batch.
// Ax buffers hold only the current CHUNK of steps; sbaseF/sbaseB are the first
// global s covered by each buffer (fwd ascending, bwd descending ranges).
__global__ __launch_bounds__(256)
void word_step(const float* __restrict__ AxF, const float* __restrict__ AxB,
               const float* __restrict__ WhhF, const float* __restrict__ WhhB,
               const float* __restrict__ Hprev, float* __restrict__ Hnext,
               float* __restrict__ Cst, float* __restrict__ enc,
               int sstep, int sbaseF, int sbaseB)
{
    const int dir = blockIdx.x >> 6;
    const int slice = blockIdx.x & 63;
    const int c0 = slice * 8;
    const int s = dir ? (S_LEN-1-sstep) : sstep;
    const int sbase = dir ? sbaseB : sbaseF;
    const float* Ax  = dir ? AxB : AxF;
    const float* Whh = dir ? WhhB : WhhF;
    const float* hp = Hprev + dir*(BATCH*HWID);
    float* hn = Hnext + dir*(BATCH*HWID);
    float* cs = Cst   + dir*(BATCH*HWID);

    __shared__ float hs_[32][BATCH+1];
    __shared__ float ws_[32][33];
    __shared__ float zbuf[BATCH][33];

    const int tid = threadIdx.x;
    const int bi = tid & 63;
    const int rg = tid >> 6;      // 0..3 (gate group), wave-uniform
    float acc[8];
    #pragma unroll
    for (int i=0;i<8;i++) acc[i]=0.f;

    for (int k0=0;k0<HWID;k0+=32){
        #pragma unroll
        for (int i=0;i<8;i++){          // h tile 64b x 32k
            int e = i*256+tid; int b = e>>5, k = e&31;
            hs_[k][b] = hp[b*HWID + k0 + k];
        }
        #pragma unroll
        for (int i=0;i<4;i++){          // Whh tile 32r x 32k
            int e = i*256+tid; int r = e>>5, k = e&31;
            int j = (r>>3)*HWID + c0 + (r&7);
            ws_[k][r] = Whh[j*HWID + k0 + k];
        }
        __syncthreads();
        #pragma unroll
        for (int k=0;k<32;k++){
            float hv = hs_[k][bi];
            #pragma unroll
            for (int i=0;i<8;i++) acc[i] += hv*ws_[k][rg*8+i];
        }
        __syncthreads();
    }
    // z = recurrent + precomputed input projection (bias folded into Ax)
    const float* axr = Ax + ((size_t)((s - sbase)*BATCH + bi))*GW + rg*HWID + c0;
    #pragma unroll
    for (int i=0;i<8;i++) zbuf[bi][rg*8+i] = acc[i] + axr[i];
    __syncthreads();
    // pointwise: 64 b x 8 cells
    for (int p = tid; p < BATCH*8; p += 256){
        int b = p>>3, ci2 = p&7;
        float zi = zbuf[b][ci2], zf = zbuf[b][8+ci2];
        float zg = zbuf[b][16+ci2], zo = zbuf[b][24+ci2];
        int cell = c0 + ci2;
        float cp = cs[b*HWID+cell];
        float cn = sigf(zf)*cp + sigf(zi)*tanhf(zg);
        float hv = sigf(zo)*tanhf(cn);
        cs[b*HWID+cell]=cn;
        hn[b*HWID+cell]=hv;
        enc[((size_t)(s*BATCH+b))*(2*HWID) + dir*HWID + cell] = hv;
    }
}

// ---------------- CRF log-likelihood (one wave per batch) ------------------------------
__global__ __launch_bounds__(64)
void crf_loss(const float* __restrict__ logits, const int* __restrict__ tags,
              const float* __restrict__ trans, const float* __restrict__ start,
              const float* __restrict__ endt, float* __restrict__ out)
{
    int b = blockIdx.x, lane = threadIdx.x;
    __shared__ float trs[TT*TT];
    __shared__ float as_[TT];
    __shared__ float red[64];
    for (int i=lane;i<TT*TT;i+=64) trs[i]=trans[i];
    __syncthreads();
    float alpha = (lane<TT) ? (start[lane] + logits[b*TT + lane]) : -1e30f;
    for (int s=1;s<S_LEN;s++){
        if (lane<TT) as_[lane]=alpha;
        __syncthreads();
        if (lane<TT){
            float m = -1e30f;
            for (int f=0;f<TT;f++){ float v=as_[f]+trs[f*TT+lane]; m = fmaxf(m,v); }
            float sm = 0.f;
            for (int f=0;f<TT;f++){ float v=as_[f]+trs[f*TT+lane]; sm += __expf(v-m); }
            alpha = m + __logf(sm) + logits[((size_t)s*BATCH+b)*TT + lane];
        }
        __syncthreads();
    }
    if (lane<TT) red[lane] = alpha + endt[lane];
    __syncthreads();
    float logZ = 0.f;
    if (lane==0){
        float m=-1e30f; for(int i=0;i<TT;i++) m=fmaxf(m,red[i]);
        float sm=0.f;   for(int i=0;i<TT;i++) sm += __expf(red[i]-m);
        logZ = m + __logf(sm);
    }
    __syncthreads();
    float sc = 0.f;
    for (int s=lane;s<S_LEN;s+=64){
        int tg = tags[s*BATCH+b];
        sc += logits[((size_t)s*BATCH+b)*TT + tg];
        if (s+1 < S_LEN){ int t2 = tags[(s+1)*BATCH+b]; sc += trs[tg*TT+t2]; }
    }
    red[lane]=sc; __syncthreads();
    if (lane==0){
        float tot = 0.f; for (int i=0;i<64;i++) tot += red[i];
        tot += start[tags[b]] + endt[tags[(S_LEN-1)*BATCH + b]];
        atomicAdd(out, -(tot - logZ));
    }
}

// ---------------- Viterbi (one wave per batch) -----------------------------------------
__global__ __launch_bounds__(64)
void viterbi_k(const float* __restrict__ logits, const float* __restrict__ trans,
               const float* __restrict__ start, const float* __restrict__ endt,
               int* __restrict__ bp, float* __restrict__ outTags)
{
    int b = blockIdx.x, lane = threadIdx.x;
    __shared__ float trs[TT*TT];
    __shared__ float vs_[TT];
    for (int i=lane;i<TT*TT;i+=64) trs[i]=trans[i];
    __syncthreads();
    float v = (lane<TT) ? (start[lane] + logits[b*TT+lane]) : -1e30f;
    for (int s=1;s<S_LEN;s++){
        if (lane<TT) vs_[lane]=v;
        __syncthreads();
        if (lane<TT){
            float best=-1e30f; int bj=0;
            for (int f=0;f<TT;f++){
                float val = vs_[f]+trs[f*TT+lane];
                if (val > best){ best=val; bj=f; }   // strict > : first max wins (jnp.argmax)
            }
            v = best + logits[((size_t)s*BATCH+b)*TT+lane];
            bp[((size_t)(s-1)*BATCH+b)*TT + lane] = bj;
        }
        __syncthreads();
    }
    if (lane<TT) vs_[lane] = v + endt[lane];
    __syncthreads();
    if (lane==0){
        float best=-1e30f; int last=0;
        for (int i=0;i<TT;i++){ if (vs_[i] > best){best=vs_[i]; last=i;} }
        int tag=last;
        outTags[b*S_LEN + (S_LEN-1)] = (float)tag;
        for (int s=S_LEN-2;s>=0;s--){
            tag = bp[((size_t)s*BATCH+b)*TT + tag];
            outTags[b*S_LEN + s] = (float)tag;
        }
    }
}

// ======================================================================================
extern "C" void kernel_launch(void* const* d_in, const int* in_sizes, int n_in,
                              void* d_out, int out_size, void* d_ws, size_t ws_size,
                              hipStream_t stream)
{
    const int* word_in = (const int*)d_in[0];
    const int* char_in = (const int*)d_in[1];
    const int* cap_in  = (const int*)d_in[2];
    const int* tag_in  = (const int*)d_in[3];
    const float* wemb  = (const float*)d_in[4];
    const float* cemb  = (const float*)d_in[5];
    const float* chemb = (const float*)d_in[6];
    const float* cWihF=(const float*)d_in[7],  *cWhhF=(const float*)d_in[8];
    const float* cBihF=(const float*)d_in[9],  *cBhhF=(const float*)d_in[10];
    const float* cWihB=(const float*)d_in[11], *cWhhB=(const float*)d_in[12];
    const float* cBihB=(const float*)d_in[13], *cBhhB=(const float*)d_in[14];
    const float* wWihF=(const float*)d_in[15], *wWhhF=(const float*)d_in[16];
    const float* wBihF=(const float*)d_in[17], *wBhhF=(const float*)d_in[18];
    const float* wWihB=(const float*)d_in[19], *wWhhB=(const float*)d_in[20];
    const float* wBihB=(const float*)d_in[21], *wBhhB=(const float*)d_in[22];
    const float* ff1W=(const float*)d_in[23],  *ff1b=(const float*)d_in[24];
    const float* ff2W=(const float*)d_in[25],  *ff2b=(const float*)d_in[26];
    const float* trans=(const float*)d_in[27];
    const float* startT=(const float*)d_in[28], *endT=(const float*)d_in[29];
    float* out = (float*)d_out;

    // ---- workspace layout (floats), ~143 MB total --------------------------
    float* W = (float*)d_ws;
    size_t o = 0;
    float* X    = W + o; o += (size_t)NSB*DD;           //  9.13M fl
    float* AXCF = W + o; o += (size_t)CROWS*GW;         //  4.19M fl (chunk Ax fwd)
    float* AXCB = W + o; o += (size_t)CROWS*GW;         //  4.19M fl (chunk Ax bwd)
    float* ENC  = W + o; o += (size_t)NSB*2*HWID;       // 16.78M fl
    float* PF   = W + o; o += 128*GC;
    float* PB   = W + o; o += 128*GC;
    float* BSF  = W + o; o += GW;
    float* BSB  = W + o; o += GW;
    float* HWb  = W + o; o += (size_t)2*2*BATCH*HWID;   // [parity][dir][b*512+c]
    float* CW   = W + o; o += (size_t)2*BATCH*HWID;     // [dir][b*512+c]
    float* LOG  = W + o; o += (size_t)NSB*TT;
    int*   BP   = (int*)(W + o); o += (size_t)(S_LEN-1)*BATCH*TT;
    // aliases (disjoint in time)
    float* ZC  = ENC;                        // char gate buffer 16384x512 (pre-scan)
    float* HCH = ENC + (size_t)NSEQ*GC;      // char h 16384x128
    float* CCH = HCH + (size_t)NSEQ*HC;      // char c 16384x128
    float* HFF = AXCF;                       // ff1 hidden 16384x512 (post-scan; spans AXCF+AXCB)

    dim3 blk(256);

    // small precomputes
    char_pmat<<<(2*128*GC+255)/256, blk, 0, stream>>>(chemb, cWihF, cWihB, PF, PB);
    bias_sum<<<(GW+255)/256, blk, 0, stream>>>(wBihF, wBhhF, wBihB, wBhhB, BSF, BSB, GW);
    x_fill<<<((NSB*304)+255)/256, blk, 0, stream>>>(word_in, cap_in, wemb, cemb, X);

    // ---- char BiLSTM --------------------------------------------------------
    dim3 gc(NSEQ/BM, GC/BN);
    zero_f<<<(NSEQ*HC*2+255)/256, blk, 0, stream>>>(HCH, NSEQ*HC*2);   // h and c contiguous
    for (int t=0;t<WLEN;t++){
        gemm_nt<<<gc, blk, 0, stream>>>(HCH, HC, cWhhF, HC, ZC, GC, NSEQ, GC, HC, nullptr, 0);
        char_pw<<<(NSEQ*HC)/256, blk, 0, stream>>>(ZC, PF, cBihF, cBhhF, char_in,
                                                   HCH, CCH, X, t, t==WLEN-1, 300);
    }
    zero_f<<<(NSEQ*HC*2+255)/256, blk, 0, stream>>>(HCH, NSEQ*HC*2);
    for (int k=0;k<WLEN;k++){
        int t = WLEN-1-k;
        gemm_nt<<<gc, blk, 0, stream>>>(HCH, HC, cWhhB, HC, ZC, GC, NSEQ, GC, HC, nullptr, 0);
        char_pw<<<(NSEQ*HC)/256, blk, 0, stream>>>(ZC, PB, cBihB, cBhhB, char_in,
                                                   HCH, CCH, X, t, k==WLEN-1, 300+HC);
    }

    // ---- word BiLSTM scans, chunked input projection ------------------------
    zero_f<<<(2*BATCH*HWID+255)/256, blk, 0, stream>>>(HWb, 2*BATCH*HWID);  // parity-0 h
    zero_f<<<(2*BATCH*HWID+255)/256, blk, 0, stream>>>(CW,  2*BATCH*HWID);
    dim3 gax(CROWS/BM, GW/BN);   // (16, 32)
    for (int j=0;j<S_LEN/CHUNK;j++){
        int sbf = j*CHUNK;                       // fwd chunk covers s in [sbf, sbf+32)
        int sbb = (S_LEN-CHUNK) - j*CHUNK;       // bwd chunk covers s in [sbb, sbb+32)
        gemm_nt<<<gax, blk, 0, stream>>>(X + (size_t)sbf*BATCH*DD, DD, wWihF, DD,
                                         AXCF, GW, CROWS, GW, DD, BSF, 0);
        gemm_nt<<<gax, blk, 0, stream>>>(X + (size_t)sbb*BATCH*DD, DD, wWihB, DD,
                                         AXCB, GW, CROWS, GW, DD, BSB, 0);
        for (int t=0;t<CHUNK;t++){
            int ss = j*CHUNK + t;
            int par = ss & 1;
            word_step<<<128, blk, 0, stream>>>(AXCF, AXCB, wWhhF, wWhhB,
                HWb + (size_t)par*2*BATCH*HWID,
                HWb + (size_t)(1-par)*2*BATCH*HWID,
                CW, ENC, ss, sbf, sbb);
        }
    }

    // ---- feed-forward head --------------------------------------------------
    dim3 g1(NSB/BM, HWID/BN);
    gemm_nt<<<g1, blk, 0, stream>>>(ENC, 2*HWID, ff1W, 2*HWID, HFF, HWID,
                                    NSB, HWID, 2*HWID, ff1b, 1);
    dim3 g2(NSB/BM, 1);
    gemm_nt<<<g2, blk, 0, stream>>>(HFF, HWID, ff2W, HWID, LOG, TT,
                                    NSB, TT, HWID, ff2b, 0);

    // ---- CRF loss + Viterbi -------------------------------------------------
    zero_f<<<1, dim3(64), 0, stream>>>(out, 1);
    crf_loss<<<BATCH, dim3(64), 0, stream>>>(LOG, tag_in, trans, startT, endT, out);
    viterbi_k<<<BATCH, dim3(64), 0, stream>>>(LOG, trans, startT, endT, BP, out+1);
}

// Round 3
// 9942.906 us; speedup vs baseline: 1.5714x; 1.5714x over previous
//
#include <hip/hip_runtime.h>
#include <math.h>

// Problem constants
#define S_LEN 256
#define BATCH 64
#define WLEN  16
#define EC    64
#define HC    128
#define HWID  512
#define TT    32
#define DD    557
#define DDP   560    // padded leading dim for X / Wih copies (float4-aligned)
#define NSEQ  16384
#define NSB   16384
#define GC    512    // 4*HC
#define GW    2048   // 4*HWID
#define CHUNK 32
#define CROWS (CHUNK*BATCH)   // 2048

__device__ __forceinline__ float sigf(float x){ return 1.f/(1.f+__expf(-x)); }

// =================== fp32 GEMM: C = act(A(MxK)*B(NxK)^T + bias) =======================
// 128x128 tile, 8x8 micro, BK=16, 256 threads. REQUIRES lda%4==0, ldb%4==0, K%16==0,
// and A/B zero-padded out to K. M,N guarded.
#define BM 128
#define BN 128
#define BK 16
__global__ __launch_bounds__(256, 2)
void gemm128(const float* __restrict__ A, int lda,
             const float* __restrict__ Bm, int ldb,
             float* __restrict__ C, int ldc,
             int M, int N, int K,
             const float* __restrict__ bias, int act)
{
    __shared__ float As[BK][BM+4];
    __shared__ float Bs[BK][BN+4];
    const int tid = threadIdx.x;
    const int m0 = blockIdx.x * BM;
    const int n0 = blockIdx.y * BN;
    const int tr = tid >> 4;   // 0..15
    const int tc = tid & 15;   // 0..15
    float acc[8][8];
    #pragma unroll
    for (int i=0;i<8;i++)
        #pragma unroll
        for(int j=0;j<8;j++) acc[i][j]=0.f;

    for (int k0 = 0; k0 < K; k0 += BK) {
        // A tile: 128 rows x 16 k = 512 float4, 2 per thread
        #pragma unroll
        for (int i=0;i<2;i++){
            int e = i*256 + tid;
            int m = e >> 2, kq = e & 3;
            int gm = m0 + m;
            float4 v = make_float4(0.f,0.f,0.f,0.f);
            if (gm < M) v = *(const float4*)&A[(size_t)gm*lda + k0 + kq*4];
            As[kq*4+0][m]=v.x; As[kq*4+1][m]=v.y; As[kq*4+2][m]=v.z; As[kq*4+3][m]=v.w;
        }
        // B tile: 128 rows x 16 k
        #pragma unroll
        for (int i=0;i<2;i++){
            int e = i*256 + tid;
            int n = e >> 2, kq = e & 3;
            int gn = n0 + n;
            float4 v = make_float4(0.f,0.f,0.f,0.f);
            if (gn < N) v = *(const float4*)&Bm[(size_t)gn*ldb + k0 + kq*4];
            Bs[kq*4+0][n]=v.x; Bs[kq*4+1][n]=v.y; Bs[kq*4+2][n]=v.z; Bs[kq*4+3][n]=v.w;
        }
        __syncthreads();
        #pragma unroll
        for (int k = 0; k < BK; k++) {
            float4 a0 = *(float4*)&As[k][tr*8];
            float4 a1 = *(float4*)&As[k][tr*8+4];
            float4 b0 = *(float4*)&Bs[k][tc*8];
            float4 b1 = *(float4*)&Bs[k][tc*8+4];
            float av[8] = {a0.x,a0.y,a0.z,a0.w,a1.x,a1.y,a1.z,a1.w};
            float bv[8] = {b0.x,b0.y,b0.z,b0.w,b1.x,b1.y,b1.z,b1.w};
            #pragma unroll
            for (int i=0;i<8;i++)
                #pragma unroll
                for (int j=0;j<8;j++)
                    acc[i][j] += av[i]*bv[j];
        }
        __syncthreads();
    }
    #pragma unroll
    for (int i=0;i<8;i++){
        int m = m0 + tr*8 + i;
        if (m >= M) continue;
        #pragma unroll
        for (int j=0;j<8;j++){
            int n = n0 + tc*8 + j;
            if (n >= N) continue;
            float v = acc[i][j];
            if (bias) v += bias[n];
            if (act==1) v = tanhf(v);
            C[(size_t)m*ldc + n] = v;
        }
    }
}

// ============ P[v][j] = char_emb(v,:) . Wih(j,:) + bih[j] + bhh[j], per dir ===========
__global__ void char_pmat(const float* __restrict__ ce,
                          const float* __restrict__ wf, const float* __restrict__ wb,
                          const float* __restrict__ bihF, const float* __restrict__ bhhF,
                          const float* __restrict__ bihB, const float* __restrict__ bhhB,
                          float* __restrict__ Pf, float* __restrict__ Pb)
{
    int gid = blockIdx.x*blockDim.x + threadIdx.x;
    if (gid >= 2*128*GC) return;
    int d = gid >> 16;
    int r = gid & 65535;
    int v = r >> 9, j = r & 511;
    const float* wW = d ? wb : wf;
    float s = 0.f;
    for (int e=0;e<EC;e++) s += ce[v*EC+e]*wW[j*EC+e];
    s += (d ? bihB[j]+bhhB[j] : bihF[j]+bhhF[j]);
    (d ? Pb : Pf)[r] = s;
}

__global__ void bias_sum(const float* __restrict__ a1, const float* __restrict__ a2,
                         const float* __restrict__ b1, const float* __restrict__ b2,
                         float* __restrict__ of, float* __restrict__ ob, int n)
{
    int i = blockIdx.x*blockDim.x+threadIdx.x;
    if (i < n){ of[i]=a1[i]+a2[i]; ob[i]=b1[i]+b2[i]; }
}

__global__ void zero_f(float* __restrict__ p, int n)
{
    int i = blockIdx.x*blockDim.x+threadIdx.x;
    if (i < n) p[i] = 0.f;
}

// pad Wih (2048 x 557) -> WP (2048 x 560), zero tail
__global__ void pad_w(const float* __restrict__ wf, const float* __restrict__ wb,
                      float* __restrict__ of, float* __restrict__ ob)
{
    int gid = blockIdx.x*blockDim.x + threadIdx.x;
    if (gid >= 2*GW*DDP) return;
    int d = gid / (GW*DDP);
    int r = gid - d*(GW*DDP);
    int j = r / DDP, k = r - j*DDP;
    float v = (k < DD) ? (d ? wb[j*DD+k] : wf[j*DD+k]) : 0.f;
    (d ? ob : of)[r] = v;
}

// ---------------- x assembly: word emb + cap emb + zero pad ---------------------------
__global__ void x_fill(const int* __restrict__ wid, const int* __restrict__ cap,
                       const float* __restrict__ wemb, const float* __restrict__ cemb,
                       float* __restrict__ X)
{
    int gid = blockIdx.x*blockDim.x+threadIdx.x;
    int sb = gid / 304, e = gid - sb*304;
    if (sb >= NSB) return;
    if (e < 300)       X[(size_t)sb*DDP + e]   = wemb[(size_t)wid[sb]*300 + e];
    else if (e == 300) X[(size_t)sb*DDP + 556] = cemb[cap[sb]];
    else               X[(size_t)sb*DDP + 556 + (e-300)] = 0.f;  // cols 557..559
}

// =================== fused char-LSTM step (GEMM + gates), both dirs ====================
// grid 1024: dir = blk>>9, seq-tile = (blk&511)*32.  Block: 32 seqs x 512 gates, K=128.
// micro: 2 seqs x (8 cells x 4 gate types) per thread.
__global__ __launch_bounds__(256, 2)
void char_step(const float* __restrict__ WhhF, const float* __restrict__ WhhB,
               const float* __restrict__ PF, const float* __restrict__ PB,
               const int* __restrict__ ci,
               float* __restrict__ CH,   // [dir][h(NSEQ*HC), c(NSEQ*HC)]
               float* __restrict__ X, int kstep)
{
    const int dir = blockIdx.x >> 9;
    const int sbase = (blockIdx.x & 511) * 32;
    const int t = dir ? (WLEN-1-kstep) : kstep;
    const int islast = (kstep == WLEN-1);
    const float* Whh = dir ? WhhB : WhhF;
    const float* P   = dir ? PB : PF;
    float* Hg = CH + (size_t)dir*(2*NSEQ*HC);
    float* Cg = Hg + (size_t)NSEQ*HC;

    __shared__ float As[16][36];
    __shared__ float Bs[16][516];

    const int tid = threadIdx.x;
    const int tr = tid >> 4;   // seq pair 0..15
    const int tc = tid & 15;   // cell group 0..15
    float acc[2][32];
    #pragma unroll
    for (int i=0;i<2;i++)
        #pragma unroll
        for (int j=0;j<32;j++) acc[i][j]=0.f;

    for (int kt=0; kt<HC; kt+=16){
        // h tile: 32 seqs x 16 k = 128 float4 (threads 0..127)
        if (tid < 128){
            int sl = tid >> 2, kq = tid & 3;
            float4 v = *(const float4*)&Hg[(size_t)(sbase+sl)*HC + kt + kq*4];
            As[kq*4+0][sl]=v.x; As[kq*4+1][sl]=v.y; As[kq*4+2][sl]=v.z; As[kq*4+3][sl]=v.w;
        }
        // W tile: 512 rows x 16 k = 2048 float4, 8 per thread
        #pragma unroll
        for (int i=0;i<8;i++){
            int e = i*256 + tid;
            int j = e >> 2, kq = e & 3;
            float4 v = *(const float4*)&Whh[(size_t)j*HC + kt + kq*4];
            Bs[kq*4+0][j]=v.x; Bs[kq*4+1][j]=v.y; Bs[kq*4+2][j]=v.z; Bs[kq*4+3][j]=v.w;
        }
        __syncthreads();
        #pragma unroll
        for (int k=0;k<16;k++){
            float a0 = As[k][tr*2], a1 = As[k][tr*2+1];
            #pragma unroll
            for (int T=0;T<4;T++){
                float4 b0 = *(float4*)&Bs[k][T*128 + tc*8];
                float4 b1 = *(float4*)&Bs[k][T*128 + tc*8 + 4];
                float bv[8] = {b0.x,b0.y,b0.z,b0.w,b1.x,b1.y,b1.z,b1.w};
                #pragma unroll
                for (int j=0;j<8;j++){
                    acc[0][T*8+j] += a0*bv[j];
                    acc[1][T*8+j] += a1*bv[j];
                }
            }
        }
        __syncthreads();
    }

    // epilogue: gates + cell update; write h (+X on last step)
    #pragma unroll
    for (int i=0;i<2;i++){
        int seq = sbase + tr*2 + i;
        int cid = ci[seq*WLEN + t];
        const float* Pr = P + (size_t)cid*GC;
        int cell0 = tc*8;
        float4 cold0 = *(float4*)&Cg[(size_t)seq*HC + cell0];
        float4 cold1 = *(float4*)&Cg[(size_t)seq*HC + cell0 + 4];
        float cold[8] = {cold0.x,cold0.y,cold0.z,cold0.w,cold1.x,cold1.y,cold1.z,cold1.w};
        float hv[8], cv[8];
        #pragma unroll
        for (int j=0;j<8;j++){
            int cell = cell0 + j;
            float zi = acc[i][j]     + Pr[cell];
            float zf = acc[i][8+j]   + Pr[128+cell];
            float zg = acc[i][16+j]  + Pr[256+cell];
            float zo = acc[i][24+j]  + Pr[384+cell];
            float cn = sigf(zf)*cold[j] + sigf(zi)*tanhf(zg);
            cv[j] = cn;
            hv[j] = sigf(zo)*tanhf(cn);
        }
        *(float4*)&Cg[(size_t)seq*HC + cell0]     = make_float4(cv[0],cv[1],cv[2],cv[3]);
        *(float4*)&Cg[(size_t)seq*HC + cell0 + 4] = make_float4(cv[4],cv[5],cv[6],cv[7]);
        *(float4*)&Hg[(size_t)seq*HC + cell0]     = make_float4(hv[0],hv[1],hv[2],hv[3]);
        *(float4*)&Hg[(size_t)seq*HC + cell0 + 4] = make_float4(hv[4],hv[5],hv[6],hv[7]);
        if (islast){
            int b = seq >> 8, s = seq & 255;
            size_t xr = (size_t)(s*BATCH + b)*DDP + 300 + dir*HC + cell0;
            *(float4*)&X[xr]     = make_float4(hv[0],hv[1],hv[2],hv[3]);
            *(float4*)&X[xr + 4] = make_float4(hv[4],hv[5],hv[6],hv[7]);
        }
    }
}

// =================== fused word-LSTM step (both dirs) ==================================
// grid 256: dir = blk>>7, slice = blk&127 -> 4 cells (16 gate rows) x 64 batch.
__global__ __launch_bounds__(256)
void word_step(const float* __restrict__ AxF, const float* __restrict__ AxB,
               const float* __restrict__ WhhF, const float* __restrict__ WhhB,
               const float* __restrict__ Hprev, float* __restrict__ Hnext,
               float* __restrict__ Cst, float* __restrict__ enc,
               int sstep, int sbaseF, int sbaseB)
{
    const int dir = blockIdx.x >> 7;
    const int slice = blockIdx.x & 127;
    const int c0 = slice * 4;
    const int s = dir ? (S_LEN-1-sstep) : sstep;
    const int sbase = dir ? sbaseB : sbaseF;
    const float* Ax  = dir ? AxB : AxF;
    const float* Whh = dir ? WhhB : WhhF;
    const float* hp = Hprev + dir*(BATCH*HWID);
    float* hn = Hnext + dir*(BATCH*HWID);
    float* cs = Cst   + dir*(BATCH*HWID);

    __shared__ float hs_[32][65];
    __shared__ float ws_[32][20];
    __shared__ float zbuf[BATCH][20];

    const int tid = threadIdx.x;
    const int bi = tid & 63;
    const int rg = tid >> 6;      // gate type 0..3, wave-uniform
    float acc[4];
    #pragma unroll
    for (int i=0;i<4;i++) acc[i]=0.f;

    for (int k0=0;k0<HWID;k0+=32){
        // h tile: 64 b x 32 k = 512 float4, 2 per thread
        #pragma unroll
        for (int i=0;i<2;i++){
            int e = i*256+tid; int b = e>>3, kq = e&7;
            float4 v = *(const float4*)&hp[b*HWID + k0 + kq*4];
            hs_[kq*4+0][b]=v.x; hs_[kq*4+1][b]=v.y; hs_[kq*4+2][b]=v.z; hs_[kq*4+3][b]=v.w;
        }
        // W tile: 16 rows x 32 k = 128 float4 (threads 0..127)
        if (tid < 128){
            int r = tid>>3, kq = tid&7;
            int j = (r>>2)*HWID + c0 + (r&3);
            float4 v = *(const float4*)&Whh[(size_t)j*HWID + k0 + kq*4];
            ws_[kq*4+0][r]=v.x; ws_[kq*4+1][r]=v.y; ws_[kq*4+2][r]=v.z; ws_[kq*4+3][r]=v.w;
        }
        __syncthreads();
        #pragma unroll
        for (int k=0;k<32;k++){
            float hv = hs_[k][bi];
            float4 w = *(float4*)&ws_[k][rg*4];
            acc[0] += hv*w.x; acc[1] += hv*w.y; acc[2] += hv*w.z; acc[3] += hv*w.w;
        }
        __syncthreads();
    }
    // z = recurrent + Ax (biases prefolded)
    {
        const float* axr = Ax + ((size_t)((s - sbase)*BATCH + bi))*GW + rg*HWID + c0;
        float4 ax = *(const float4*)axr;
        *(float4*)&zbuf[bi][rg*4] = make_float4(acc[0]+ax.x, acc[1]+ax.y, acc[2]+ax.z, acc[3]+ax.w);
    }
    __syncthreads();
    // pointwise: 64 b x 4 cells = 256 threads exactly
    {
        int b = tid >> 2, ci2 = tid & 3;
        float zi = zbuf[b][ci2], zf = zbuf[b][4+ci2];
        float zg = zbuf[b][8+ci2], zo = zbuf[b][12+ci2];
        int cell = c0 + ci2;
        float cp = cs[b*HWID+cell];
        float cn = sigf(zf)*cp + sigf(zi)*tanhf(zg);
        float hv = sigf(zo)*tanhf(cn);
        cs[b*HWID+cell]=cn;
        hn[b*HWID+cell]=hv;
        enc[((size_t)(s*BATCH+b))*(2*HWID) + dir*HWID + cell] = hv;
    }
}

// ---------------- CRF log-likelihood (one wave per batch) ------------------------------
__global__ __launch_bounds__(64)
void crf_loss(const float* __restrict__ logits, const int* __restrict__ tags,
              const float* __restrict__ trans, const float* __restrict__ start,
              const float* __restrict__ endt, float* __restrict__ out)
{
    int b = blockIdx.x, lane = threadIdx.x;
    __shared__ float trs[TT*TT];
    __shared__ float as_[TT];
    __shared__ float red[64];
    for (int i=lane;i<TT*TT;i+=64) trs[i]=trans[i];
    __syncthreads();
    float alpha = (lane<TT) ? (start[lane] + logits[b*TT + lane]) : -1e30f;
    for (int s=1;s<S_LEN;s++){
        if (lane<TT) as_[lane]=alpha;
        __syncthreads();
        if (lane<TT){
            float m = -1e30f;
            for (int f=0;f<TT;f++){ float v=as_[f]+trs[f*TT+lane]; m = fmaxf(m,v); }
            float sm = 0.f;
            for (int f=0;f<TT;f++){ float v=as_[f]+trs[f*TT+lane]; sm += __expf(v-m); }
            alpha = m + __logf(sm) + logits[((size_t)s*BATCH+b)*TT + lane];
        }
        __syncthreads();
    }
    if (lane<TT) red[lane] = alpha + endt[lane];
    __syncthreads();
    float logZ = 0.f;
    if (lane==0){
        float m=-1e30f; for(int i=0;i<TT;i++) m=fmaxf(m,red[i]);
        float sm=0.f;   for(int i=0;i<TT;i++) sm += __expf(red[i]-m);
        logZ = m + __logf(sm);
    }
    __syncthreads();
    float sc = 0.f;
    for (int s=lane;s<S_LEN;s+=64){
        int tg = tags[s*BATCH+b];
        sc += logits[((size_t)s*BATCH+b)*TT + tg];
        if (s+1 < S_LEN){ int t2 = tags[(s+1)*BATCH+b]; sc += trs[tg*TT+t2]; }
    }
    red[lane]=sc; __syncthreads();
    if (lane==0){
        float tot = 0.f; for (int i=0;i<64;i++) tot += red[i];
        tot += start[tags[b]] + endt[tags[(S_LEN-1)*BATCH + b]];
        atomicAdd(out, -(tot - logZ));
    }
}

// ---------------- Viterbi (one wave per batch) -----------------------------------------
__global__ __launch_bounds__(64)
void viterbi_k(const float* __restrict__ logits, const float* __restrict__ trans,
               const float* __restrict__ start, const float* __restrict__ endt,
               int* __restrict__ bp, float* __restrict__ outTags)
{
    int b = blockIdx.x, lane = threadIdx.x;
    __shared__ float trs[TT*TT];
    __shared__ float vs_[TT];
    for (int i=lane;i<TT*TT;i+=64) trs[i]=trans[i];
    __syncthreads();
    float v = (lane<TT) ? (start[lane] + logits[b*TT+lane]) : -1e30f;
    for (int s=1;s<S_LEN;s++){
        if (lane<TT) vs_[lane]=v;
        __syncthreads();
        if (lane<TT){
            float best=-1e30f; int bj=0;
            for (int f=0;f<TT;f++){
                float val = vs_[f]+trs[f*TT+lane];
                if (val > best){ best=val; bj=f; }   // strict >: first max (jnp.argmax)
            }
            v = best + logits[((size_t)s*BATCH+b)*TT+lane];
            bp[((size_t)(s-1)*BATCH+b)*TT + lane] = bj;
        }
        __syncthreads();
    }
    if (lane<TT) vs_[lane] = v + endt[lane];
    __syncthreads();
    if (lane==0){
        float best=-1e30f; int last=0;
        for (int i=0;i<TT;i++){ if (vs_[i] > best){best=vs_[i]; last=i;} }
        int tag=last;
        outTags[b*S_LEN + (S_LEN-1)] = (float)tag;
        for (int s=S_LEN-2;s>=0;s--){
            tag = bp[((size_t)s*BATCH+b)*TT + tag];
            outTags[b*S_LEN + s] = (float)tag;
        }
    }
}

// ======================================================================================
extern "C" void kernel_launch(void* const* d_in, const int* in_sizes, int n_in,
                              void* d_out, int out_size, void* d_ws, size_t ws_size,
                              hipStream_t stream)
{
    const int* word_in = (const int*)d_in[0];
    const int* char_in = (const int*)d_in[1];
    const int* cap_in  = (const int*)d_in[2];
    const int* tag_in  = (const int*)d_in[3];
    const float* wemb  = (const float*)d_in[4];
    const float* cemb  = (const float*)d_in[5];
    const float* chemb = (const float*)d_in[6];
    const float* cWihF=(const float*)d_in[7],  *cWhhF=(const float*)d_in[8];
    const float* cBihF=(const float*)d_in[9],  *cBhhF=(const float*)d_in[10];
    const float* cWihB=(const float*)d_in[11], *cWhhB=(const float*)d_in[12];
    const float* cBihB=(const float*)d_in[13], *cBhhB=(const float*)d_in[14];
    const float* wWihF=(const float*)d_in[15], *wWhhF=(const float*)d_in[16];
    const float* wBihF=(const float*)d_in[17], *wBhhF=(const float*)d_in[18];
    const float* wWihB=(const float*)d_in[19], *wWhhB=(const float*)d_in[20];
    const float* wBihB=(const float*)d_in[21], *wBhhB=(const float*)d_in[22];
    const float* ff1W=(const float*)d_in[23],  *ff1b=(const float*)d_in[24];
    const float* ff2W=(const float*)d_in[25],  *ff2b=(const float*)d_in[26];
    const float* trans=(const float*)d_in[27];
    const float* startT=(const float*)d_in[28], *endT=(const float*)d_in[29];
    float* out = (float*)d_out;

    // ---- workspace layout (floats), ~149 MB -------------------------------
    float* W = (float*)d_ws;
    size_t o = 0;
    float* X    = W + o; o += (size_t)NSB*DDP;          //  9.18M
    float* AXCF = W + o; o += (size_t)CROWS*GW;         //  4.19M
    float* AXCB = W + o; o += (size_t)CROWS*GW;         //  4.19M
    float* ENC  = W + o; o += (size_t)NSB*2*HWID;       // 16.78M
    float* PF   = W + o; o += 128*GC;
    float* PB   = W + o; o += 128*GC;
    float* BSF  = W + o; o += GW;
    float* BSB  = W + o; o += GW;
    float* HWb  = W + o; o += (size_t)2*2*BATCH*HWID;
    float* CW   = W + o; o += (size_t)2*BATCH*HWID;
    float* WPF  = W + o; o += (size_t)GW*DDP;           //  1.15M
    float* WPB  = W + o; o += (size_t)GW*DDP;           //  1.15M
    // aliases (disjoint in time)
    float* CH  = ENC;            // char h/c [dir][h,c]: 4*NSEQ*HC = 8.39M <= ENC
    float* HFF = AXCF;           // ff1 hidden 16384x512 = 8.39M (AXCF+AXCB span)
    float* LOG = X;              // logits 16384x32 (X dead after word phase)
    int*   BP  = (int*)(X + (size_t)1024*1024);  // 0.48M ints, inside X

    dim3 blk(256);

    // ---- precomputes -------------------------------------------------------
    char_pmat<<<(2*128*GC+255)/256, blk, 0, stream>>>(chemb, cWihF, cWihB,
                                                      cBihF, cBhhF, cBihB, cBhhB, PF, PB);
    x_fill<<<((NSB*304)+255)/256, blk, 0, stream>>>(word_in, cap_in, wemb, cemb, X);
    bias_sum<<<(GW+255)/256, blk, 0, stream>>>(wBihF, wBhhF, wBihB, wBhhB, BSF, BSB, GW);
    pad_w<<<(2*GW*DDP+255)/256, blk, 0, stream>>>(wWihF, wWihB, WPF, WPB);

    // ---- char BiLSTM (fused, both dirs per launch) -------------------------
    zero_f<<<(4*NSEQ*HC+255)/256, blk, 0, stream>>>(CH, 4*NSEQ*HC);
    for (int k=0;k<WLEN;k++){
        char_step<<<1024, blk, 0, stream>>>(cWhhF, cWhhB, PF, PB, char_in, CH, X, k);
    }

    // ---- word BiLSTM, chunked input projection -----------------------------
    zero_f<<<(2*BATCH*HWID+255)/256, blk, 0, stream>>>(HWb, 2*BATCH*HWID);
    zero_f<<<(2*BATCH*HWID+255)/256, blk, 0, stream>>>(CW,  2*BATCH*HWID);
    dim3 gax(CROWS/BM, GW/BN);   // (16, 16)
    for (int j=0;j<S_LEN/CHUNK;j++){
        int sbf = j*CHUNK;
        int sbb = (S_LEN-CHUNK) - j*CHUNK;
        gemm128<<<gax, blk, 0, stream>>>(X + (size_t)sbf*BATCH*DDP, DDP, WPF, DDP,
                                         AXCF, GW, CROWS, GW, DDP, BSF, 0);
        gemm128<<<gax, blk, 0, stream>>>(X + (size_t)sbb*BATCH*DDP, DDP, WPB, DDP,
                                         AXCB, GW, CROWS, GW, DDP, BSB, 0);
        for (int t=0;t<CHUNK;t++){
            int ss = j*CHUNK + t;
            int par = ss & 1;
            word_step<<<256, blk, 0, stream>>>(AXCF, AXCB, wWhhF, wWhhB,
                HWb + (size_t)par*2*BATCH*HWID,
                HWb + (size_t)(1-par)*2*BATCH*HWID,
                CW, ENC, ss, sbf, sbb);
        }
    }

    // ---- feed-forward head -------------------------------------------------
    dim3 g1(NSB/BM, HWID/BN);    // (128, 4)
    gemm128<<<g1, blk, 0, stream>>>(ENC, 2*HWID, ff1W, 2*HWID, HFF, HWID,
                                    NSB, HWID, 2*HWID, ff1b, 1);
    dim3 g2(NSB/BM, 1);
    gemm128<<<g2, blk, 0, stream>>>(HFF, HWID, ff2W, HWID, LOG, TT,
                                    NSB, TT, HWID, ff2b, 0);

    // ---- CRF loss + Viterbi ------------------------------------------------
    zero_f<<<1, dim3(64), 0, stream>>>(out, 1);
    crf_loss<<<BATCH, dim3(64), 0, stream>>>(LOG, tag_in, trans, startT, endT, out);
    viterbi_k<<<BATCH, dim3(64), 0, stream>>>(LOG, trans, startT, endT, BP, out+1);
}